// Round 18
// baseline (107.297 us; speedup 1.0000x reference)
//
#include <hip/hip_runtime.h>
#include <math.h>

typedef unsigned short u16;
typedef unsigned int u32;
typedef short short8 __attribute__((ext_vector_type(8)));
typedef float f32x4 __attribute__((ext_vector_type(4)));
typedef float f4 __attribute__((ext_vector_type(4)));
typedef unsigned short u16x4 __attribute__((ext_vector_type(4)));
typedef unsigned int u32x2 __attribute__((ext_vector_type(2)));

// ---------- helpers ----------
__device__ __forceinline__ u16 f2bf(float f) {
  unsigned u = __builtin_bit_cast(unsigned, f);
  u += 0x7fffu + ((u >> 16) & 1u);
  return (u16)(u >> 16);
}

__device__ __forceinline__ float bf2f(u16 v) {
  return __builtin_bit_cast(float, (u32)v << 16);
}

__device__ __forceinline__ u32 cvtpk_bf16(float a, float b) {
  u32 r;
  asm("v_cvt_pk_bf16_f32 %0, %1, %2" : "=v"(r) : "v"(a), "v"(b));
  return r;  // lo16 = bf16(a), hi16 = bf16(b)
}

__device__ __forceinline__ float exp2r(float x) {  // raw v_exp_f32: 1 inst, exp2(-inf)=0
  float r;
  asm("v_exp_f32 %0, %1" : "=v"(r) : "v"(x));
  return r;
}

__device__ __forceinline__ void gload16(const void* g, void* l) {
  __builtin_amdgcn_global_load_lds((const __attribute__((address_space(1))) void*)g,
                                   (__attribute__((address_space(3))) void*)l, 16, 0, 0);
}

// ---------- merged prologue: convert x + transpose both weights ----------
__global__ __launch_bounds__(256) void prep_kernel(const float* __restrict__ x,
                                                   u16* __restrict__ xb,
                                                   const float* __restrict__ Wa,
                                                   u16* __restrict__ Wat,
                                                   const float* __restrict__ Wp,
                                                   u16* __restrict__ Wpt, float qscale) {
  __shared__ float t[32][33];
  const int bx = blockIdx.x, tid = threadIdx.x;
  if (bx < 1024) {
    const int n4 = 4194304 / 4;
    for (int i = bx * 256 + tid; i < n4; i += 1024 * 256) {
      f4 v = ((const f4*)x)[i];
      u16x4 o;
      o[0] = f2bf(v[0]); o[1] = f2bf(v[1]); o[2] = f2bf(v[2]); o[3] = f2bf(v[3]);
      ((u16x4*)xb)[i] = o;
    }
    return;
  }
  const float* in;
  u16* out;
  int R, C, j0, i0, qcols;
  if (bx < 4096) {
    int bid = bx - 1024;                       // 96 x 32 tiles
    in = Wa; out = Wat; R = 1024; C = 3072; qcols = 1024;
    j0 = (bid % 96) * 32; i0 = (bid / 96) * 32;
  } else {
    int bid = bx - 4096;                       // 32 x 32 tiles
    in = Wp; out = Wpt; R = 1024; C = 1024; qcols = 0;
    j0 = (bid % 32) * 32; i0 = (bid / 32) * 32;
  }
  const int tx = tid & 31, ty = tid >> 5;  // 32 x 8
#pragma unroll
  for (int k = 0; k < 4; ++k) t[ty + 8 * k][tx] = in[(size_t)(i0 + ty + 8 * k) * C + j0 + tx];
  __syncthreads();
#pragma unroll
  for (int k = 0; k < 4; ++k) {
    int orow = j0 + ty + 8 * k;
    float v = t[tx][ty + 8 * k];
    if (orow < qcols) v *= qscale;
    out[(size_t)orow * R + i0 + tx] = f2bf(v);
  }
}

// ---------- GEMM: C[m][n] = sum_k A[m][k] * Bt[n][k], bf16 in, fp32 acc ----------
// MODE 2: qkv GEMM — cols<2048 -> bf16 qkv; cols>=2048 (V) -> write transposed
// into Vt[bh][d][t] directly (fused V-transpose). 128x128 tile, 4 waves.
template <int MODE>
__global__ __launch_bounds__(256) void gemm_kernel(const u16* __restrict__ A,
                                                   const u16* __restrict__ Bt,
                                                   void* __restrict__ Cv,
                                                   u16* __restrict__ Vt, int N, int K) {
  __shared__ __align__(16) u16 lA[128 * 64];
  __shared__ __align__(16) u16 lB[128 * 64];
  const int tid = threadIdx.x;
  const int w = tid >> 6, lane = tid & 63, lo = lane & 15, hi = lane >> 4;
  const int wm = w >> 1, wn = w & 1;
  const int m0 = blockIdx.y * 128, n0 = blockIdx.x * 128;
  f32x4 acc[4][4] = {};
  const int nkt = K >> 6;
  for (int kt = 0; kt < nkt; ++kt) {
    const int k0 = kt * 64;
#pragma unroll
    for (int c = 0; c < 4; ++c) {
      int flat = tid + c * 256;
      int r = flat >> 3, kc = flat & 7;
      int kcs = kc ^ (r & 7);
      gload16(A + (size_t)(m0 + r) * K + k0 + kcs * 8, (char*)lA + flat * 16);
      gload16(Bt + (size_t)(n0 + r) * K + k0 + kcs * 8, (char*)lB + flat * 16);
    }
    __syncthreads();
#pragma unroll
    for (int kk = 0; kk < 2; ++kk) {
      short8 af[4], bf[4];
#pragma unroll
      for (int mf = 0; mf < 4; ++mf) {
        int row = wm * 64 + mf * 16 + lo;
        int addr = (row * 128 + kk * 64 + hi * 16) ^ ((row & 7) << 4);
        af[mf] = *(const short8*)((const char*)lA + addr);
      }
#pragma unroll
      for (int nf = 0; nf < 4; ++nf) {
        int row = wn * 64 + nf * 16 + lo;
        int addr = (row * 128 + kk * 64 + hi * 16) ^ ((row & 7) << 4);
        bf[nf] = *(const short8*)((const char*)lB + addr);
      }
#pragma unroll
      for (int mf = 0; mf < 4; ++mf)
#pragma unroll
        for (int nf = 0; nf < 4; ++nf)
          acc[mf][nf] = __builtin_amdgcn_mfma_f32_16x16x32_bf16(af[mf], bf[nf], acc[mf][nf], 0, 0, 0);
    }
    __syncthreads();
  }
#pragma unroll
  for (int mf = 0; mf < 4; ++mf)
#pragma unroll
    for (int nf = 0; nf < 4; ++nf) {
      const int row0 = m0 + wm * 64 + mf * 16 + hi * 4;
      const int col = n0 + wn * 64 + nf * 16 + lo;
      if (MODE == 0) {
#pragma unroll
        for (int r = 0; r < 4; ++r)
          ((float*)Cv)[(size_t)(row0 + r) * N + col] = acc[mf][nf][r];
      } else {
        if (col < 2048) {  // wave-uniform (128-col stripes align with the 2048 split)
#pragma unroll
          for (int r = 0; r < 4; ++r)
            ((u16*)Cv)[(size_t)(row0 + r) * N + col] = f2bf(acc[mf][nf][r]);
        } else {
          const int dl = col - 2048;
          const int bh = (row0 >> 11) * 16 + (dl >> 6);
          const int d = dl & 63, t = row0 & 2047;
          u16x4 pk;
#pragma unroll
          for (int r = 0; r < 4; ++r) pk[r] = f2bf(acc[mf][nf][r]);
          *(u16x4*)&Vt[(size_t)bh * 131072 + d * 2048 + t] = pk;
        }
      }
    }
}

// ---------- projection GEMM: 128x64 tile, 4 waves (2Mx2N), f32 out ----------
__global__ __launch_bounds__(256) void gemm_proj(const u16* __restrict__ A,
                                                 const u16* __restrict__ Bt,
                                                 float* __restrict__ C, int N, int K) {
  __shared__ __align__(16) u16 lA[128 * 64];  // 16KB
  __shared__ __align__(16) u16 lB[64 * 64];   // 8KB
  const int tid = threadIdx.x;
  const int w = tid >> 6, lane = tid & 63, lo = lane & 15, hi = lane >> 4;
  const int wm = w >> 1, wn = w & 1;  // wave grid 2M x 2N: 64 rows x 32 cols each
  const int m0 = blockIdx.y * 128, n0 = blockIdx.x * 64;
  f32x4 acc[4][2] = {};
  const int nkt = K >> 6;
  for (int kt = 0; kt < nkt; ++kt) {
    const int k0 = kt * 64;
#pragma unroll
    for (int c = 0; c < 4; ++c) {  // A: 16KB
      int flat = tid + c * 256;
      int r = flat >> 3, kc = flat & 7;
      int kcs = kc ^ (r & 7);
      gload16(A + (size_t)(m0 + r) * K + k0 + kcs * 8, (char*)lA + flat * 16);
    }
#pragma unroll
    for (int c = 0; c < 2; ++c) {  // B: 8KB
      int flat = tid + c * 256;
      int r = flat >> 3, kc = flat & 7;
      int kcs = kc ^ (r & 7);
      gload16(Bt + (size_t)(n0 + r) * K + k0 + kcs * 8, (char*)lB + flat * 16);
    }
    __syncthreads();
#pragma unroll
    for (int kk = 0; kk < 2; ++kk) {
      short8 af[4], bf[2];
#pragma unroll
      for (int mf = 0; mf < 4; ++mf) {
        int row = wm * 64 + mf * 16 + lo;
        int addr = (row * 128 + kk * 64 + hi * 16) ^ ((row & 7) << 4);
        af[mf] = *(const short8*)((const char*)lA + addr);
      }
#pragma unroll
      for (int nf = 0; nf < 2; ++nf) {
        int row = wn * 32 + nf * 16 + lo;
        int addr = (row * 128 + kk * 64 + hi * 16) ^ ((row & 7) << 4);
        bf[nf] = *(const short8*)((const char*)lB + addr);
      }
#pragma unroll
      for (int mf = 0; mf < 4; ++mf)
#pragma unroll
        for (int nf = 0; nf < 2; ++nf)
          acc[mf][nf] = __builtin_amdgcn_mfma_f32_16x16x32_bf16(af[mf], bf[nf], acc[mf][nf], 0, 0, 0);
    }
    __syncthreads();
  }
#pragma unroll
  for (int mf = 0; mf < 4; ++mf)
#pragma unroll
    for (int nf = 0; nf < 2; ++nf) {
      const int row0 = m0 + wm * 64 + mf * 16 + hi * 4;
      const int col = n0 + wn * 32 + nf * 16 + lo;
#pragma unroll
      for (int r = 0; r < 4; ++r)
        C[(size_t)(row0 + r) * N + col] = acc[mf][nf][r];
    }
}

// ---------- flash attention: cooperative LDS staging, 4 warps x 32 q-rows ----------
// 512 blocks x 4 waves (256 thr). Block id: j=id>>5 -> qb = (j<8)?15-2j:2(j-8)
// (co-resident pairs sum to constant work), bh = id&31 (id%8=bh%8 -> XCD L2 pin).
// Block owns 128 q rows, 32 PER WARP (2 m-groups): halves the number of warps
// redundantly reading the SAME K/V fragments from LDS (R17 diagnosis: LDS-read
// throughput bound, 8x redundancy). K/V staged once per tile (global_load_lds,
// pre-swizzled source + XOR-swizzled ds_read), double-buffered, ONE barrier/tile.
// Fixed-reference softmax p=exp2(s); L via ones-column PV MFMA; per-warp epilogue.
__global__ __launch_bounds__(256) void attn_kernel(const u16* __restrict__ qkv,
                                                   const u16* __restrict__ Vt,
                                                   u16* __restrict__ yb) {
  __shared__ __align__(16) u16 lK[2][64 * 64];  // [buf][row t][col d-chunk swizzled]
  __shared__ __align__(16) u16 lV[2][64 * 64];  // [buf][row d][col t-chunk swizzled]
  __shared__ __align__(16) u16 pl[4][32][72];   // per-warp P tile (32 q rows)
  const int tid = threadIdx.x, w = tid >> 6, lane = tid & 63;
  const int lo = lane & 15, hi = lane >> 4;
  const int id = blockIdx.x;
  const int j = id >> 5;
  const int qb = (j < 8) ? (15 - 2 * j) : (2 * (j - 8));
  const int bh = id & 31, b = bh >> 4, h = bh & 15;
  const int wq0 = qb * 128 + w * 32;  // warp's first q row (owns 32 rows)

  // staging coords: 2 chunks/thread per matrix; chunk c -> flat = tid + c*256,
  // row sr = flat>>3, 16B chunk skc = flat&7, source chunk XOR-swizzled
  int kSrc[2], vSrc[2];
#pragma unroll
  for (int c = 0; c < 2; ++c) {
    const int flat = tid + c * 256;
    const int sr = flat >> 3, skc = flat & 7;
    const int skcs = (skc ^ (sr & 7)) * 8;
    kSrc[c] = (b * 2048 + sr) * 3072 + 1024 + h * 64 + skcs;  // + t0*3072
    vSrc[c] = bh * 131072 + sr * 2048 + skcs;                 // + t0
  }

  // Q fragments: 2 m-groups of 16 rows
  short8 qf[2][2];
#pragma unroll
  for (int m = 0; m < 2; ++m) {
    const int qbase = (b * 2048 + wq0 + m * 16 + lo) * 3072 + h * 64 + hi * 8;
    qf[m][0] = *(const short8*)(qkv + qbase);
    qf[m][1] = *(const short8*)(qkv + qbase + 32);
  }

  short8 vones;
#pragma unroll
  for (int i = 0; i < 8; ++i) vones[i] = (short)0x3F80;  // bf16 1.0

  f32x4 yacc[2][4] = {};
  f32x4 lacc[2] = {};

  const int nt = 2 * qb + 2;
  // prologue: stage tile 0 -> buf 0
#pragma unroll
  for (int c = 0; c < 2; ++c) {
    gload16(qkv + kSrc[c], (char*)lK[0] + (tid + c * 256) * 16);
    gload16(Vt + vSrc[c], (char*)lV[0] + (tid + c * 256) * 16);
  }
  asm volatile("s_waitcnt vmcnt(0)" ::: "memory");
  __syncthreads();

  int buf = 0;
#pragma unroll 1
  for (int it = 0; it < nt; ++it) {
    const int t0 = it * 64;
    if (it + 1 < nt) {  // stage next tile into the other buffer (async)
#pragma unroll
      for (int c = 0; c < 2; ++c) {
        gload16(qkv + (kSrc[c] + (t0 + 64) * 3072), (char*)lK[buf ^ 1] + (tid + c * 256) * 16);
        gload16(Vt + (vSrc[c] + t0 + 64), (char*)lV[buf ^ 1] + (tid + c * 256) * 16);
      }
    }
    if (t0 <= wq0 + 31) {  // warp-uniform: tile not fully masked for this warp
      const char* lKb = (const char*)lK[buf];
      const char* lVb = (const char*)lV[buf];
      f32x4 st[4][2] = {};  // st[n][m][r] = S^T[k=t0+n*16+4hi+r][q=wq0+m*16+lo]
#pragma unroll
      for (int kk = 0; kk < 2; ++kk) {
        short8 kf[4];
#pragma unroll
        for (int n = 0; n < 4; ++n)
          kf[n] = *(const short8*)(lKb + ((n * 16 + lo) * 128 + (((kk * 4 + hi) ^ (lo & 7)) * 16)));
#pragma unroll
        for (int n = 0; n < 4; ++n)
#pragma unroll
          for (int m = 0; m < 2; ++m)
            st[n][m] = __builtin_amdgcn_mfma_f32_16x16x32_bf16(kf[n], qf[m][kk], st[n][m], 0, 0, 0);
      }

      if (t0 + 63 > wq0) {  // diagonal-straddling tile for this warp
#pragma unroll
        for (int m = 0; m < 2; ++m) {
          const int q = wq0 + m * 16 + lo;
#pragma unroll
          for (int n = 0; n < 4; ++n)
#pragma unroll
            for (int r = 0; r < 4; ++r) {
              const int k = t0 + n * 16 + hi * 4 + r;
              st[n][m][r] = (k <= q) ? st[n][m][r] : -INFINITY;
            }
        }
      }
      // p = exp2(s): no shift, no max, no row-sum; pack -> P LDS
#pragma unroll
      for (int m = 0; m < 2; ++m)
#pragma unroll
        for (int n = 0; n < 4; ++n) {
          u32x2 pw;
          pw[0] = cvtpk_bf16(exp2r(st[n][m][0]), exp2r(st[n][m][1]));
          pw[1] = cvtpk_bf16(exp2r(st[n][m][2]), exp2r(st[n][m][3]));
          *(u32x2*)&pl[w][m * 16 + lo][n * 16 + hi * 4] = pw;
        }
      // V fragments from LDS + PV (+ ones-column L); shared across both m-groups
      short8 pa0[2], pa1[2];
#pragma unroll
      for (int m = 0; m < 2; ++m) {
        pa0[m] = *(const short8*)&pl[w][m * 16 + lo][hi * 8];
        pa1[m] = *(const short8*)&pl[w][m * 16 + lo][32 + hi * 8];
      }
      short8 vf0[4], vf1[4];
#pragma unroll
      for (int nf = 0; nf < 4; ++nf) {
        vf0[nf] = *(const short8*)(lVb + ((nf * 16 + lo) * 128 + (((hi) ^ (lo & 7)) * 16)));
        vf1[nf] = *(const short8*)(lVb + ((nf * 16 + lo) * 128 + (((4 + hi) ^ (lo & 7)) * 16)));
      }
#pragma unroll
      for (int m = 0; m < 2; ++m) {
#pragma unroll
        for (int nf = 0; nf < 4; ++nf)
          yacc[m][nf] = __builtin_amdgcn_mfma_f32_16x16x32_bf16(pa0[m], vf0[nf], yacc[m][nf], 0, 0, 0);
        lacc[m] = __builtin_amdgcn_mfma_f32_16x16x32_bf16(pa0[m], vones, lacc[m], 0, 0, 0);
      }
#pragma unroll
      for (int m = 0; m < 2; ++m) {
#pragma unroll
        for (int nf = 0; nf < 4; ++nf)
          yacc[m][nf] = __builtin_amdgcn_mfma_f32_16x16x32_bf16(pa1[m], vf1[nf], yacc[m][nf], 0, 0, 0);
        lacc[m] = __builtin_amdgcn_mfma_f32_16x16x32_bf16(pa1[m], vones, lacc[m], 0, 0, 0);
      }
    }
    asm volatile("s_waitcnt vmcnt(0)" ::: "memory");  // next-tile staging landed
    __syncthreads();                                   // all warps done with buf
    buf ^= 1;
  }

  // per-warp epilogue: O = yacc / L  (lacc[m][r] = L[wq0+m*16+4hi+r])
#pragma unroll
  for (int m = 0; m < 2; ++m) {
    f32x4 inv;
#pragma unroll
    for (int r = 0; r < 4; ++r) inv[r] = 1.f / lacc[m][r];
#pragma unroll
    for (int nf = 0; nf < 4; ++nf)
#pragma unroll
      for (int r = 0; r < 4; ++r)
        yb[(b * 2048 + wq0 + m * 16 + hi * 4 + r) * 1024 + h * 64 + nf * 16 + lo] =
            f2bf(yacc[m][nf][r] * inv[r]);
  }
}

extern "C" void kernel_launch(void* const* d_in, const int* in_sizes, int n_in,
                              void* d_out, int out_size, void* d_ws, size_t ws_size,
                              hipStream_t stream) {
  const float* x = (const float*)d_in[0];    // [4096][1024]
  const float* Wa = (const float*)d_in[1];   // [1024][3072]
  const float* Wp = (const float*)d_in[2];   // [1024][1024]
  char* ws = (char*)d_ws;
  u16* xb   = (u16*)(ws);              // [4096][1024] bf16
  u16* Wat  = (u16*)(ws + 8388608);    // [3072][1024] bf16 (W_attn^T, Q rows pre-scaled)
  u16* Wpt  = (u16*)(ws + 14680064);   // [1024][1024] bf16 (W_proj^T)
  u16* qkvb = (u16*)(ws + 16777216);   // [4096][3072] bf16 (V third unused)
  u16* Vt   = (u16*)(ws + 41943040);   // [32][64][2048] bf16 (written by gemm1 epilogue)
  u16* yb   = (u16*)(ws + 50331648);   // [4096][1024] bf16

  const float CS = 0.03125f * 1.44269504088896f;  // rsqrt(1024) * log2(e)
  prep_kernel<<<5120, 256, 0, stream>>>(x, xb, Wa, Wat, Wp, Wpt, CS);
  gemm_kernel<2><<<dim3(24, 32), 256, 0, stream>>>(xb, Wat, (void*)qkvb, Vt, 3072, 1024);
  attn_kernel<<<512, 256, 0, stream>>>(qkvb, Vt, yb);
  gemm_proj<<<dim3(16, 32), 256, 0, stream>>>(yb, Wpt, (float*)d_out, 1024, 1024);
}

// Round 19
// 105.049 us; speedup vs baseline: 1.0214x; 1.0214x over previous
//
#include <hip/hip_runtime.h>
#include <math.h>

typedef unsigned short u16;
typedef unsigned int u32;
typedef short short8 __attribute__((ext_vector_type(8)));
typedef short s16x4 __attribute__((ext_vector_type(4)));
typedef float f32x4 __attribute__((ext_vector_type(4)));
typedef float f4 __attribute__((ext_vector_type(4)));
typedef unsigned short u16x4 __attribute__((ext_vector_type(4)));
typedef unsigned int u32x4 __attribute__((ext_vector_type(4)));

// ---------- helpers ----------
__device__ __forceinline__ u16 f2bf(float f) {
  unsigned u = __builtin_bit_cast(unsigned, f);
  u += 0x7fffu + ((u >> 16) & 1u);
  return (u16)(u >> 16);
}

__device__ __forceinline__ u32 cvtpk_bf16(float a, float b) {
  u32 r;
  asm("v_cvt_pk_bf16_f32 %0, %1, %2" : "=v"(r) : "v"(a), "v"(b));
  return r;  // lo16 = bf16(a), hi16 = bf16(b)
}

__device__ __forceinline__ float exp2r(float x) {  // raw v_exp_f32: 1 inst, exp2(-inf)=0
  float r;
  asm("v_exp_f32 %0, %1" : "=v"(r) : "v"(x));
  return r;
}

__device__ __forceinline__ void gload16(const void* g, void* l) {
  __builtin_amdgcn_global_load_lds((const __attribute__((address_space(1))) void*)g,
                                   (__attribute__((address_space(3))) void*)l, 16, 0, 0);
}

// ---------- merged prologue: convert x + transpose both weights ----------
__global__ __launch_bounds__(256) void prep_kernel(const float* __restrict__ x,
                                                   u16* __restrict__ xb,
                                                   const float* __restrict__ Wa,
                                                   u16* __restrict__ Wat,
                                                   const float* __restrict__ Wp,
                                                   u16* __restrict__ Wpt, float qscale) {
  __shared__ float t[32][33];
  const int bx = blockIdx.x, tid = threadIdx.x;
  if (bx < 1024) {
    const int n4 = 4194304 / 4;
    for (int i = bx * 256 + tid; i < n4; i += 1024 * 256) {
      f4 v = ((const f4*)x)[i];
      u16x4 o;
      o[0] = f2bf(v[0]); o[1] = f2bf(v[1]); o[2] = f2bf(v[2]); o[3] = f2bf(v[3]);
      ((u16x4*)xb)[i] = o;
    }
    return;
  }
  const float* in;
  u16* out;
  int R, C, j0, i0, qcols;
  if (bx < 4096) {
    int bid = bx - 1024;                       // 96 x 32 tiles
    in = Wa; out = Wat; R = 1024; C = 3072; qcols = 1024;
    j0 = (bid % 96) * 32; i0 = (bid / 96) * 32;
  } else {
    int bid = bx - 4096;                       // 32 x 32 tiles
    in = Wp; out = Wpt; R = 1024; C = 1024; qcols = 0;
    j0 = (bid % 32) * 32; i0 = (bid / 32) * 32;
  }
  const int tx = tid & 31, ty = tid >> 5;  // 32 x 8
#pragma unroll
  for (int k = 0; k < 4; ++k) t[ty + 8 * k][tx] = in[(size_t)(i0 + ty + 8 * k) * C + j0 + tx];
  __syncthreads();
#pragma unroll
  for (int k = 0; k < 4; ++k) {
    int orow = j0 + ty + 8 * k;
    float v = t[tx][ty + 8 * k];
    if (orow < qcols) v *= qscale;
    out[(size_t)orow * R + i0 + tx] = f2bf(v);
  }
}

// ---------- qkv GEMM: 128x128 tile, XCD-patch swizzled 1D grid (768 blocks) ----------
// cols<2048 -> bf16 qkv; cols>=2048 (V) -> write transposed into Vt[bh][d][t].
// Swizzle: xcd = id&7 owns an 8y x 12x patch (A 2MB + B 3MB ~ L2-resident per XCD).
__global__ __launch_bounds__(256) void gemm_qkv(const u16* __restrict__ A,
                                                const u16* __restrict__ Bt,
                                                u16* __restrict__ qkvb,
                                                u16* __restrict__ Vt, int N, int K) {
  __shared__ __align__(16) u16 lA[128 * 64];
  __shared__ __align__(16) u16 lB[128 * 64];
  const int tid = threadIdx.x;
  const int w = tid >> 6, lane = tid & 63, lo = lane & 15, hi = lane >> 4;
  const int wm = w >> 1, wn = w & 1;
  const int id = blockIdx.x;
  const int xcd = id & 7, kk0 = id >> 3;     // kk0 in [0,96)
  const int py = kk0 & 7, px = kk0 >> 3;     // 8 x 12 patch
  const int m0 = (8 * (xcd >> 1) + py) * 128;  // y-tile in [0,32)
  const int n0 = (12 * (xcd & 1) + px) * 128;  // x-tile in [0,24)
  f32x4 acc[4][4] = {};
  const int nkt = K >> 6;
  for (int kt = 0; kt < nkt; ++kt) {
    const int k0 = kt * 64;
#pragma unroll
    for (int c = 0; c < 4; ++c) {
      int flat = tid + c * 256;
      int r = flat >> 3, kc = flat & 7;
      int kcs = kc ^ (r & 7);
      gload16(A + (size_t)(m0 + r) * K + k0 + kcs * 8, (char*)lA + flat * 16);
      gload16(Bt + (size_t)(n0 + r) * K + k0 + kcs * 8, (char*)lB + flat * 16);
    }
    __syncthreads();
#pragma unroll
    for (int kk = 0; kk < 2; ++kk) {
      short8 af[4], bf[4];
#pragma unroll
      for (int mf = 0; mf < 4; ++mf) {
        int row = wm * 64 + mf * 16 + lo;
        int addr = (row * 128 + kk * 64 + hi * 16) ^ ((row & 7) << 4);
        af[mf] = *(const short8*)((const char*)lA + addr);
      }
#pragma unroll
      for (int nf = 0; nf < 4; ++nf) {
        int row = wn * 64 + nf * 16 + lo;
        int addr = (row * 128 + kk * 64 + hi * 16) ^ ((row & 7) << 4);
        bf[nf] = *(const short8*)((const char*)lB + addr);
      }
#pragma unroll
      for (int mf = 0; mf < 4; ++mf)
#pragma unroll
        for (int nf = 0; nf < 4; ++nf)
          acc[mf][nf] = __builtin_amdgcn_mfma_f32_16x16x32_bf16(af[mf], bf[nf], acc[mf][nf], 0, 0, 0);
    }
    __syncthreads();
  }
#pragma unroll
  for (int mf = 0; mf < 4; ++mf)
#pragma unroll
    for (int nf = 0; nf < 4; ++nf) {
      const int row0 = m0 + wm * 64 + mf * 16 + hi * 4;
      const int col = n0 + wn * 64 + nf * 16 + lo;
      if (col < 2048) {  // block-uniform (n0 multiple of 128)
#pragma unroll
        for (int r = 0; r < 4; ++r)
          qkvb[(size_t)(row0 + r) * N + col] = f2bf(acc[mf][nf][r]);
      } else {
        const int dl = col - 2048;
        const int bh = (row0 >> 11) * 16 + (dl >> 6);
        const int d = dl & 63, t = row0 & 2047;
        u16x4 pk;
#pragma unroll
        for (int r = 0; r < 4; ++r) pk[r] = f2bf(acc[mf][nf][r]);
        *(u16x4*)&Vt[(size_t)bh * 131072 + d * 2048 + t] = pk;
      }
    }
}

// ---------- projection GEMM: 128x64 tile, 4 waves (2Mx2N), f32 out ----------
__global__ __launch_bounds__(256) void gemm_proj(const u16* __restrict__ A,
                                                 const u16* __restrict__ Bt,
                                                 float* __restrict__ C, int N, int K) {
  __shared__ __align__(16) u16 lA[128 * 64];  // 16KB
  __shared__ __align__(16) u16 lB[64 * 64];   // 8KB
  const int tid = threadIdx.x;
  const int w = tid >> 6, lane = tid & 63, lo = lane & 15, hi = lane >> 4;
  const int wm = w >> 1, wn = w & 1;  // wave grid 2M x 2N: 64 rows x 32 cols each
  const int m0 = blockIdx.y * 128, n0 = blockIdx.x * 64;
  f32x4 acc[4][2] = {};
  const int nkt = K >> 6;
  for (int kt = 0; kt < nkt; ++kt) {
    const int k0 = kt * 64;
#pragma unroll
    for (int c = 0; c < 4; ++c) {  // A: 16KB
      int flat = tid + c * 256;
      int r = flat >> 3, kc = flat & 7;
      int kcs = kc ^ (r & 7);
      gload16(A + (size_t)(m0 + r) * K + k0 + kcs * 8, (char*)lA + flat * 16);
    }
#pragma unroll
    for (int c = 0; c < 2; ++c) {  // B: 8KB
      int flat = tid + c * 256;
      int r = flat >> 3, kc = flat & 7;
      int kcs = kc ^ (r & 7);
      gload16(Bt + (size_t)(n0 + r) * K + k0 + kcs * 8, (char*)lB + flat * 16);
    }
    __syncthreads();
#pragma unroll
    for (int kk = 0; kk < 2; ++kk) {
      short8 af[4], bf[2];
#pragma unroll
      for (int mf = 0; mf < 4; ++mf) {
        int row = wm * 64 + mf * 16 + lo;
        int addr = (row * 128 + kk * 64 + hi * 16) ^ ((row & 7) << 4);
        af[mf] = *(const short8*)((const char*)lA + addr);
      }
#pragma unroll
      for (int nf = 0; nf < 2; ++nf) {
        int row = wn * 32 + nf * 16 + lo;
        int addr = (row * 128 + kk * 64 + hi * 16) ^ ((row & 7) << 4);
        bf[nf] = *(const short8*)((const char*)lB + addr);
      }
#pragma unroll
      for (int mf = 0; mf < 4; ++mf)
#pragma unroll
        for (int nf = 0; nf < 2; ++nf)
          acc[mf][nf] = __builtin_amdgcn_mfma_f32_16x16x32_bf16(af[mf], bf[nf], acc[mf][nf], 0, 0, 0);
    }
    __syncthreads();
  }
#pragma unroll
  for (int mf = 0; mf < 4; ++mf)
#pragma unroll
    for (int nf = 0; nf < 2; ++nf) {
      const int row0 = m0 + wm * 64 + mf * 16 + hi * 4;
      const int col = n0 + wn * 32 + nf * 16 + lo;
#pragma unroll
      for (int r = 0; r < 4; ++r)
        C[(size_t)(row0 + r) * N + col] = acc[mf][nf][r];
    }
}

// ---------- flash attention: cooperative staging + in-register P (no P-LDS) ----------
// R15 geometry: 512 blocks x 8 waves; j=id>>5 -> qb = (j<8)?15-2j:2(j-8); bh=id&31.
// NEW: PV consumes P directly from registers. The MFMA contraction is invariant to
// any k-permutation applied to BOTH operands; with virtual order
//   k(hi,e) = 16*(e>>2) + 4*hi + (e&3)   (+32 for the 2nd half)
// the A-operand is exactly the lane's own st[n][r] packed in natural order (8 cvtpk,
// ZERO cross-lane / LDS ops), and V picks up the same permutation via two b64 LDS
// reads per fragment (chunks hi>>1 and 2+(hi>>1), byte offset 8*(hi&1), XOR-swizzled).
// Deletes 8 ds_write + 2 ds_read + 2 lgkm waits per warp-tile and the 18KB P-LDS.
__global__ __launch_bounds__(512) void attn_kernel(const u16* __restrict__ qkv,
                                                   const u16* __restrict__ Vt,
                                                   u16* __restrict__ yb) {
  __shared__ __align__(16) u16 lK[2][64 * 64];  // [buf][row t][col d-chunk swizzled]
  __shared__ __align__(16) u16 lV[2][64 * 64];  // [buf][row d][col t-chunk swizzled]
  const int tid = threadIdx.x, w = tid >> 6, lane = tid & 63;
  const int lo = lane & 15, hi = lane >> 4;
  const int id = blockIdx.x;
  const int j = id >> 5;
  const int qb = (j < 8) ? (15 - 2 * j) : (2 * (j - 8));
  const int bh = id & 31, b = bh >> 4, h = bh & 15;
  const int wq0 = qb * 128 + w * 16;

  // staging coords: thread -> (row sr, 16B chunk skc), source chunk XOR-swizzled
  const int sr = tid >> 3, skc = tid & 7;
  const int skcs = (skc ^ (sr & 7)) * 8;
  const int kSrc = (b * 2048 + sr) * 3072 + 1024 + h * 64 + skcs;  // + t0*3072
  const int vSrc = bh * 131072 + sr * 2048 + skcs;                 // + t0
  const int sdst = tid * 16;                                       // linear LDS bytes

  // Q fragments (16 rows per warp)
  const int qbase = (b * 2048 + wq0 + lo) * 3072 + h * 64 + hi * 8;
  const short8 qf0 = *(const short8*)(qkv + qbase);
  const short8 qf1 = *(const short8*)(qkv + qbase + 32);

  short8 vones;
#pragma unroll
  for (int i = 0; i < 8; ++i) vones[i] = (short)0x3F80;  // bf16 1.0

  f32x4 yacc[4] = {};
  f32x4 lacc = {};

  const int nt = 2 * qb + 2;
  // prologue: stage tile 0 -> buf 0
  gload16(qkv + kSrc, (char*)lK[0] + sdst);
  gload16(Vt + vSrc, (char*)lV[0] + sdst);
  asm volatile("s_waitcnt vmcnt(0)" ::: "memory");
  __syncthreads();

  int buf = 0;
#pragma unroll 1
  for (int it = 0; it < nt; ++it) {
    const int t0 = it * 64;
    if (it + 1 < nt) {  // stage next tile into the other buffer (async)
      gload16(qkv + (kSrc + (t0 + 64) * 3072), (char*)lK[buf ^ 1] + sdst);
      gload16(Vt + (vSrc + t0 + 64), (char*)lV[buf ^ 1] + sdst);
    }
    if (t0 <= wq0 + 15) {  // warp-uniform: tile not fully masked for this warp
      const char* lKb = (const char*)lK[buf];
      const char* lVb = (const char*)lV[buf];
      // K fragments from LDS (XOR-swizzled chunks)
      short8 kf[4][2];
#pragma unroll
      for (int n = 0; n < 4; ++n)
#pragma unroll
        for (int kk = 0; kk < 2; ++kk)
          kf[n][kk] = *(const short8*)(lKb + ((n * 16 + lo) * 128 + (((kk * 4 + hi) ^ (lo & 7)) * 16)));
      f32x4 st[4] = {};  // st[n][r] = S^T[k=t0+n*16+4hi+r][q=wq0+lo] (log2 units)
#pragma unroll
      for (int n = 0; n < 4; ++n)
        st[n] = __builtin_amdgcn_mfma_f32_16x16x32_bf16(kf[n][0], qf0, st[n], 0, 0, 0);
#pragma unroll
      for (int n = 0; n < 4; ++n)
        st[n] = __builtin_amdgcn_mfma_f32_16x16x32_bf16(kf[n][1], qf1, st[n], 0, 0, 0);

      if (t0 + 63 > wq0) {  // diagonal-straddling tile for this warp
        const int q = wq0 + lo;
#pragma unroll
        for (int n = 0; n < 4; ++n)
#pragma unroll
          for (int r = 0; r < 4; ++r) {
            const int k = t0 + n * 16 + hi * 4 + r;
            st[n][r] = (k <= q) ? st[n][r] : -INFINITY;
          }
      }

      // P in-register: pa0 covers virtual k(hi,e)=16*(e>>2)+4hi+(e&3) (n=0,1),
      // pa1 the same +32 (n=2,3). Pure lane-local pack: 8 cvtpk, no LDS.
      u32x4 w0, w1;
#pragma unroll
      for (int n = 0; n < 2; ++n) {
        w0[2 * n]     = cvtpk_bf16(exp2r(st[n][0]), exp2r(st[n][1]));
        w0[2 * n + 1] = cvtpk_bf16(exp2r(st[n][2]), exp2r(st[n][3]));
      }
#pragma unroll
      for (int n = 0; n < 2; ++n) {
        w1[2 * n]     = cvtpk_bf16(exp2r(st[n + 2][0]), exp2r(st[n + 2][1]));
        w1[2 * n + 1] = cvtpk_bf16(exp2r(st[n + 2][2]), exp2r(st[n + 2][3]));
      }
      const short8 pa0 = __builtin_bit_cast(short8, w0);
      const short8 pa1 = __builtin_bit_cast(short8, w1);

      // V fragments with the SAME virtual-k permutation: two b64 reads per fragment.
      // half hh: element e<4 -> t-off = hh*32 + 4hi + e  (chunk hh*4 + (hi>>1))
      //          element e>=4 -> t-off = hh*32 + 16 + 4hi + (e-4) (chunk +2)
      const int cb0 = hi >> 1, boff = (hi & 1) * 8;
#pragma unroll
      for (int hh = 0; hh < 2; ++hh) {
        const short8 pa = hh ? pa1 : pa0;
        short8 vf[4];
#pragma unroll
        for (int nf = 0; nf < 4; ++nf) {
          const char* rowp = lVb + (nf * 16 + lo) * 128;
          const int sw = (lo & 7);
          s16x4 va = *(const s16x4*)(rowp + (((hh * 4 + cb0) ^ sw) * 16) + boff);
          s16x4 vb = *(const s16x4*)(rowp + (((hh * 4 + cb0 + 2) ^ sw) * 16) + boff);
          vf[nf] = __builtin_shufflevector(va, vb, 0, 1, 2, 3, 4, 5, 6, 7);
        }
#pragma unroll
        for (int nf = 0; nf < 4; ++nf)
          yacc[nf] = __builtin_amdgcn_mfma_f32_16x16x32_bf16(pa, vf[nf], yacc[nf], 0, 0, 0);
        lacc = __builtin_amdgcn_mfma_f32_16x16x32_bf16(pa, vones, lacc, 0, 0, 0);
      }
    }
    asm volatile("s_waitcnt vmcnt(0)" ::: "memory");  // next-tile staging landed
    __syncthreads();                                   // all warps done with buf
    buf ^= 1;
  }

  // per-warp epilogue: O = yacc / L  (L = lacc[r], identical across lanes' cols)
  f32x4 inv;
#pragma unroll
  for (int r = 0; r < 4; ++r) inv[r] = 1.f / lacc[r];
#pragma unroll
  for (int nf = 0; nf < 4; ++nf)
#pragma unroll
    for (int r = 0; r < 4; ++r)
      yb[(b * 2048 + wq0 + hi * 4 + r) * 1024 + h * 64 + nf * 16 + lo] =
          f2bf(yacc[nf][r] * inv[r]);
}

extern "C" void kernel_launch(void* const* d_in, const int* in_sizes, int n_in,
                              void* d_out, int out_size, void* d_ws, size_t ws_size,
                              hipStream_t stream) {
  const float* x = (const float*)d_in[0];    // [4096][1024]
  const float* Wa = (const float*)d_in[1];   // [1024][3072]
  const float* Wp = (const float*)d_in[2];   // [1024][1024]
  char* ws = (char*)d_ws;
  u16* xb   = (u16*)(ws);              // [4096][1024] bf16
  u16* Wat  = (u16*)(ws + 8388608);    // [3072][1024] bf16 (W_attn^T, Q rows pre-scaled)
  u16* Wpt  = (u16*)(ws + 14680064);   // [1024][1024] bf16 (W_proj^T)
  u16* qkvb = (u16*)(ws + 16777216);   // [4096][3072] bf16 (V third unused)
  u16* Vt   = (u16*)(ws + 41943040);   // [32][64][2048] bf16 (written by gemm_qkv epilogue)
  u16* yb   = (u16*)(ws + 50331648);   // [4096][1024] bf16

  const float CS = 0.03125f * 1.44269504088896f;  // rsqrt(1024) * log2(e)
  prep_kernel<<<5120, 256, 0, stream>>>(x, xb, Wa, Wat, Wp, Wpt, CS);
  gemm_qkv<<<768, 256, 0, stream>>>(xb, Wat, qkvb, Vt, 3072, 1024);
  attn_kernel<<<512, 512, 0, stream>>>(qkvb, Vt, yb);
  gemm_proj<<<dim3(16, 32), 256, 0, stream>>>(yb, Wpt, (float*)d_out, 1024, 1024);
}

// Round 20
// 98.692 us; speedup vs baseline: 1.0872x; 1.0644x over previous
//
#include <hip/hip_runtime.h>
#include <math.h>

typedef unsigned short u16;
typedef unsigned int u32;
typedef short short8 __attribute__((ext_vector_type(8)));
typedef float f32x4 __attribute__((ext_vector_type(4)));
typedef float f4 __attribute__((ext_vector_type(4)));
typedef unsigned short u16x4 __attribute__((ext_vector_type(4)));
typedef unsigned int u32x4 __attribute__((ext_vector_type(4)));

// ---------- helpers ----------
__device__ __forceinline__ u16 f2bf(float f) {
  unsigned u = __builtin_bit_cast(unsigned, f);
  u += 0x7fffu + ((u >> 16) & 1u);
  return (u16)(u >> 16);
}

__device__ __forceinline__ u32 cvtpk_bf16(float a, float b) {
  u32 r;
  asm("v_cvt_pk_bf16_f32 %0, %1, %2" : "=v"(r) : "v"(a), "v"(b));
  return r;  // lo16 = bf16(a), hi16 = bf16(b)
}

__device__ __forceinline__ float exp2r(float x) {  // raw v_exp_f32: 1 inst, exp2(-inf)=0
  float r;
  asm("v_exp_f32 %0, %1" : "=v"(r) : "v"(x));
  return r;
}

__device__ __forceinline__ void gload16(const void* g, void* l) {
  __builtin_amdgcn_global_load_lds((const __attribute__((address_space(1))) void*)g,
                                   (__attribute__((address_space(3))) void*)l, 16, 0, 0);
}

// ---------- merged prologue: convert x + transpose both weights ----------
__global__ __launch_bounds__(256) void prep_kernel(const float* __restrict__ x,
                                                   u16* __restrict__ xb,
                                                   const float* __restrict__ Wa,
                                                   u16* __restrict__ Wat,
                                                   const float* __restrict__ Wp,
                                                   u16* __restrict__ Wpt, float qscale) {
  __shared__ float t[32][33];
  const int bx = blockIdx.x, tid = threadIdx.x;
  if (bx < 1024) {
    const int n4 = 4194304 / 4;
    for (int i = bx * 256 + tid; i < n4; i += 1024 * 256) {
      f4 v = ((const f4*)x)[i];
      u16x4 o;
      o[0] = f2bf(v[0]); o[1] = f2bf(v[1]); o[2] = f2bf(v[2]); o[3] = f2bf(v[3]);
      ((u16x4*)xb)[i] = o;
    }
    return;
  }
  const float* in;
  u16* out;
  int R, C, j0, i0, qcols;
  if (bx < 4096) {
    int bid = bx - 1024;                       // 96 x 32 tiles
    in = Wa; out = Wat; R = 1024; C = 3072; qcols = 1024;
    j0 = (bid % 96) * 32; i0 = (bid / 96) * 32;
  } else {
    int bid = bx - 4096;                       // 32 x 32 tiles
    in = Wp; out = Wpt; R = 1024; C = 1024; qcols = 0;
    j0 = (bid % 32) * 32; i0 = (bid / 32) * 32;
  }
  const int tx = tid & 31, ty = tid >> 5;  // 32 x 8
#pragma unroll
  for (int k = 0; k < 4; ++k) t[ty + 8 * k][tx] = in[(size_t)(i0 + ty + 8 * k) * C + j0 + tx];
  __syncthreads();
#pragma unroll
  for (int k = 0; k < 4; ++k) {
    int orow = j0 + ty + 8 * k;
    float v = t[tx][ty + 8 * k];
    if (orow < qcols) v *= qscale;
    out[(size_t)orow * R + i0 + tx] = f2bf(v);
  }
}

// ---------- qkv GEMM: 128x128 tile, XCD-patch swizzled 1D grid (768 blocks) ----------
// cols<2048 -> bf16 qkv; cols>=2048 (V) -> write transposed AND virtual-k permuted
// into Vt[bh][d][p]: within each 64-t tile, t = 32hh+16s+4h'+r stored at
// p = 32hh+8h'+4s+r. This makes attn's PV B-fragment (virtual k order
// k(hi,e)=16(e>>2)+4hi+(e&3)) a SINGLE b128 LDS read at chunk 4hh+hi.
__global__ __launch_bounds__(256) void gemm_qkv(const u16* __restrict__ A,
                                                const u16* __restrict__ Bt,
                                                u16* __restrict__ qkvb,
                                                u16* __restrict__ Vt, int N, int K) {
  __shared__ __align__(16) u16 lA[128 * 64];
  __shared__ __align__(16) u16 lB[128 * 64];
  const int tid = threadIdx.x;
  const int w = tid >> 6, lane = tid & 63, lo = lane & 15, hi = lane >> 4;
  const int wm = w >> 1, wn = w & 1;
  const int id = blockIdx.x;
  const int xcd = id & 7, kk0 = id >> 3;     // kk0 in [0,96)
  const int py = kk0 & 7, px = kk0 >> 3;     // 8 x 12 patch
  const int m0 = (8 * (xcd >> 1) + py) * 128;  // y-tile in [0,32)
  const int n0 = (12 * (xcd & 1) + px) * 128;  // x-tile in [0,24)
  f32x4 acc[4][4] = {};
  const int nkt = K >> 6;
  for (int kt = 0; kt < nkt; ++kt) {
    const int k0 = kt * 64;
#pragma unroll
    for (int c = 0; c < 4; ++c) {
      int flat = tid + c * 256;
      int r = flat >> 3, kc = flat & 7;
      int kcs = kc ^ (r & 7);
      gload16(A + (size_t)(m0 + r) * K + k0 + kcs * 8, (char*)lA + flat * 16);
      gload16(Bt + (size_t)(n0 + r) * K + k0 + kcs * 8, (char*)lB + flat * 16);
    }
    __syncthreads();
#pragma unroll
    for (int kk = 0; kk < 2; ++kk) {
      short8 af[4], bf[4];
#pragma unroll
      for (int mf = 0; mf < 4; ++mf) {
        int row = wm * 64 + mf * 16 + lo;
        int addr = (row * 128 + kk * 64 + hi * 16) ^ ((row & 7) << 4);
        af[mf] = *(const short8*)((const char*)lA + addr);
      }
#pragma unroll
      for (int nf = 0; nf < 4; ++nf) {
        int row = wn * 64 + nf * 16 + lo;
        int addr = (row * 128 + kk * 64 + hi * 16) ^ ((row & 7) << 4);
        bf[nf] = *(const short8*)((const char*)lB + addr);
      }
#pragma unroll
      for (int mf = 0; mf < 4; ++mf)
#pragma unroll
        for (int nf = 0; nf < 4; ++nf)
          acc[mf][nf] = __builtin_amdgcn_mfma_f32_16x16x32_bf16(af[mf], bf[nf], acc[mf][nf], 0, 0, 0);
    }
    __syncthreads();
  }
#pragma unroll
  for (int mf = 0; mf < 4; ++mf)
#pragma unroll
    for (int nf = 0; nf < 4; ++nf) {
      const int row0 = m0 + wm * 64 + mf * 16 + hi * 4;
      const int col = n0 + wn * 64 + nf * 16 + lo;
      if (col < 2048) {  // block-uniform (n0 multiple of 128)
#pragma unroll
        for (int r = 0; r < 4; ++r)
          qkvb[(size_t)(row0 + r) * N + col] = f2bf(acc[mf][nf][r]);
      } else {
        const int dl = col - 2048;
        const int bh = (row0 >> 11) * 16 + (dl >> 6);
        const int d = dl & 63, t4 = row0 & 2047;  // 4-aligned t
        // virtual-k permutation within the 64-t tile: p4 = base + 32hh + 8h' + 4s
        const int p4 = (t4 & ~63) + 32 * ((t4 >> 5) & 1) + 8 * ((t4 >> 2) & 3) +
                       4 * ((t4 >> 4) & 1);
        u16x4 pk;
#pragma unroll
        for (int r = 0; r < 4; ++r) pk[r] = f2bf(acc[mf][nf][r]);
        *(u16x4*)&Vt[(size_t)bh * 131072 + d * 2048 + p4] = pk;
      }
    }
}

// ---------- projection GEMM: 128x64 tile, 4 waves (2Mx2N), f32 out ----------
__global__ __launch_bounds__(256) void gemm_proj(const u16* __restrict__ A,
                                                 const u16* __restrict__ Bt,
                                                 float* __restrict__ C, int N, int K) {
  __shared__ __align__(16) u16 lA[128 * 64];  // 16KB
  __shared__ __align__(16) u16 lB[64 * 64];   // 8KB
  const int tid = threadIdx.x;
  const int w = tid >> 6, lane = tid & 63, lo = lane & 15, hi = lane >> 4;
  const int wm = w >> 1, wn = w & 1;  // wave grid 2M x 2N: 64 rows x 32 cols each
  const int m0 = blockIdx.y * 128, n0 = blockIdx.x * 64;
  f32x4 acc[4][2] = {};
  const int nkt = K >> 6;
  for (int kt = 0; kt < nkt; ++kt) {
    const int k0 = kt * 64;
#pragma unroll
    for (int c = 0; c < 4; ++c) {  // A: 16KB
      int flat = tid + c * 256;
      int r = flat >> 3, kc = flat & 7;
      int kcs = kc ^ (r & 7);
      gload16(A + (size_t)(m0 + r) * K + k0 + kcs * 8, (char*)lA + flat * 16);
    }
#pragma unroll
    for (int c = 0; c < 2; ++c) {  // B: 8KB
      int flat = tid + c * 256;
      int r = flat >> 3, kc = flat & 7;
      int kcs = kc ^ (r & 7);
      gload16(Bt + (size_t)(n0 + r) * K + k0 + kcs * 8, (char*)lB + flat * 16);
    }
    __syncthreads();
#pragma unroll
    for (int kk = 0; kk < 2; ++kk) {
      short8 af[4], bf[2];
#pragma unroll
      for (int mf = 0; mf < 4; ++mf) {
        int row = wm * 64 + mf * 16 + lo;
        int addr = (row * 128 + kk * 64 + hi * 16) ^ ((row & 7) << 4);
        af[mf] = *(const short8*)((const char*)lA + addr);
      }
#pragma unroll
      for (int nf = 0; nf < 2; ++nf) {
        int row = wn * 32 + nf * 16 + lo;
        int addr = (row * 128 + kk * 64 + hi * 16) ^ ((row & 7) << 4);
        bf[nf] = *(const short8*)((const char*)lB + addr);
      }
#pragma unroll
      for (int mf = 0; mf < 4; ++mf)
#pragma unroll
        for (int nf = 0; nf < 2; ++nf)
          acc[mf][nf] = __builtin_amdgcn_mfma_f32_16x16x32_bf16(af[mf], bf[nf], acc[mf][nf], 0, 0, 0);
    }
    __syncthreads();
  }
#pragma unroll
  for (int mf = 0; mf < 4; ++mf)
#pragma unroll
    for (int nf = 0; nf < 2; ++nf) {
      const int row0 = m0 + wm * 64 + mf * 16 + hi * 4;
      const int col = n0 + wn * 32 + nf * 16 + lo;
#pragma unroll
      for (int r = 0; r < 4; ++r)
        C[(size_t)(row0 + r) * N + col] = acc[mf][nf][r];
    }
}

// ---------- flash attention: cooperative staging + in-register P + permuted-V b128 ----------
// R15 geometry: 512 blocks x 8 waves; j=id>>5 -> qb = (j<8)?15-2j:2(j-8); bh=id&31.
// P never touches LDS: with virtual k-order k(hi,e)=16(e>>2)+4hi+(e&3) (+32 for the
// 2nd half), the PV A-operand is the lane's own st values (8 cvtpk). V is stored
// (by gemm_qkv) with the matching permutation, so each B-fragment is ONE b128 read
// at chunk (4hh+hi)^sw — same conflict-free geometry as the K reads (R15-proven).
__global__ __launch_bounds__(512) void attn_kernel(const u16* __restrict__ qkv,
                                                   const u16* __restrict__ Vt,
                                                   u16* __restrict__ yb) {
  __shared__ __align__(16) u16 lK[2][64 * 64];  // [buf][row t][col d-chunk swizzled]
  __shared__ __align__(16) u16 lV[2][64 * 64];  // [buf][row d][col p-chunk swizzled]
  const int tid = threadIdx.x, w = tid >> 6, lane = tid & 63;
  const int lo = lane & 15, hi = lane >> 4;
  const int id = blockIdx.x;
  const int j = id >> 5;
  const int qb = (j < 8) ? (15 - 2 * j) : (2 * (j - 8));
  const int bh = id & 31, b = bh >> 4, h = bh & 15;
  const int wq0 = qb * 128 + w * 16;

  // staging coords: thread -> (row sr, 16B chunk skc), source chunk XOR-swizzled
  const int sr = tid >> 3, skc = tid & 7;
  const int skcs = (skc ^ (sr & 7)) * 8;
  const int kSrc = (b * 2048 + sr) * 3072 + 1024 + h * 64 + skcs;  // + t0*3072
  const int vSrc = bh * 131072 + sr * 2048 + skcs;                 // + t0
  const int sdst = tid * 16;                                       // linear LDS bytes

  // Q fragments (16 rows per warp)
  const int qbase = (b * 2048 + wq0 + lo) * 3072 + h * 64 + hi * 8;
  const short8 qf0 = *(const short8*)(qkv + qbase);
  const short8 qf1 = *(const short8*)(qkv + qbase + 32);

  short8 vones;
#pragma unroll
  for (int i = 0; i < 8; ++i) vones[i] = (short)0x3F80;  // bf16 1.0

  f32x4 yacc[4] = {};
  f32x4 lacc = {};

  const int nt = 2 * qb + 2;
  // prologue: stage tile 0 -> buf 0
  gload16(qkv + kSrc, (char*)lK[0] + sdst);
  gload16(Vt + vSrc, (char*)lV[0] + sdst);
  asm volatile("s_waitcnt vmcnt(0)" ::: "memory");
  __syncthreads();

  int buf = 0;
#pragma unroll 1
  for (int it = 0; it < nt; ++it) {
    const int t0 = it * 64;
    if (it + 1 < nt) {  // stage next tile into the other buffer (async)
      gload16(qkv + (kSrc + (t0 + 64) * 3072), (char*)lK[buf ^ 1] + sdst);
      gload16(Vt + (vSrc + t0 + 64), (char*)lV[buf ^ 1] + sdst);
    }
    if (t0 <= wq0 + 15) {  // warp-uniform: tile not fully masked for this warp
      const char* lKb = (const char*)lK[buf];
      const char* lVb = (const char*)lV[buf];
      // K fragments from LDS (XOR-swizzled chunks)
      short8 kf[4][2];
#pragma unroll
      for (int n = 0; n < 4; ++n)
#pragma unroll
        for (int kk = 0; kk < 2; ++kk)
          kf[n][kk] = *(const short8*)(lKb + ((n * 16 + lo) * 128 + (((kk * 4 + hi) ^ (lo & 7)) * 16)));
      f32x4 st[4] = {};  // st[n][r] = S^T[k=t0+n*16+4hi+r][q=wq0+lo] (log2 units)
#pragma unroll
      for (int n = 0; n < 4; ++n)
        st[n] = __builtin_amdgcn_mfma_f32_16x16x32_bf16(kf[n][0], qf0, st[n], 0, 0, 0);
#pragma unroll
      for (int n = 0; n < 4; ++n)
        st[n] = __builtin_amdgcn_mfma_f32_16x16x32_bf16(kf[n][1], qf1, st[n], 0, 0, 0);

      if (t0 + 63 > wq0) {  // diagonal-straddling tile for this warp
        const int q = wq0 + lo;
#pragma unroll
        for (int n = 0; n < 4; ++n)
#pragma unroll
          for (int r = 0; r < 4; ++r) {
            const int k = t0 + n * 16 + hi * 4 + r;
            st[n][r] = (k <= q) ? st[n][r] : -INFINITY;
          }
      }

      // P in-register (virtual k order): element e of half hh = st[2*hh + (e>>2)][e&3]
      u32x4 w0, w1;
#pragma unroll
      for (int n = 0; n < 2; ++n) {
        w0[2 * n]     = cvtpk_bf16(exp2r(st[n][0]), exp2r(st[n][1]));
        w0[2 * n + 1] = cvtpk_bf16(exp2r(st[n][2]), exp2r(st[n][3]));
      }
#pragma unroll
      for (int n = 0; n < 2; ++n) {
        w1[2 * n]     = cvtpk_bf16(exp2r(st[n + 2][0]), exp2r(st[n + 2][1]));
        w1[2 * n + 1] = cvtpk_bf16(exp2r(st[n + 2][2]), exp2r(st[n + 2][3]));
      }
      const short8 pa0 = __builtin_bit_cast(short8, w0);
      const short8 pa1 = __builtin_bit_cast(short8, w1);

      // V fragments: storage is virtual-k permuted -> ONE b128 at chunk (4hh+hi)^sw
      const int sw = lo & 7;
#pragma unroll
      for (int hh = 0; hh < 2; ++hh) {
        const short8 pa = hh ? pa1 : pa0;
        short8 vf[4];
#pragma unroll
        for (int nf = 0; nf < 4; ++nf)
          vf[nf] = *(const short8*)(lVb + ((nf * 16 + lo) * 128 + (((hh * 4 + hi) ^ sw) * 16)));
#pragma unroll
        for (int nf = 0; nf < 4; ++nf)
          yacc[nf] = __builtin_amdgcn_mfma_f32_16x16x32_bf16(pa, vf[nf], yacc[nf], 0, 0, 0);
        lacc = __builtin_amdgcn_mfma_f32_16x16x32_bf16(pa, vones, lacc, 0, 0, 0);
      }
    }
    asm volatile("s_waitcnt vmcnt(0)" ::: "memory");  // next-tile staging landed
    __syncthreads();                                   // all warps done with buf
    buf ^= 1;
  }

  // per-warp epilogue: O = yacc / L  (L = lacc[r], identical across lanes' cols)
  f32x4 inv;
#pragma unroll
  for (int r = 0; r < 4; ++r) inv[r] = 1.f / lacc[r];
#pragma unroll
  for (int nf = 0; nf < 4; ++nf)
#pragma unroll
    for (int r = 0; r < 4; ++r)
      yb[(b * 2048 + wq0 + hi * 4 + r) * 1024 + h * 64 + nf * 16 + lo] =
          f2bf(yacc[nf][r] * inv[r]);
}

extern "C" void kernel_launch(void* const* d_in, const int* in_sizes, int n_in,
                              void* d_out, int out_size, void* d_ws, size_t ws_size,
                              hipStream_t stream) {
  const float* x = (const float*)d_in[0];    // [4096][1024]
  const float* Wa = (const float*)d_in[1];   // [1024][3072]
  const float* Wp = (const float*)d_in[2];   // [1024][1024]
  char* ws = (char*)d_ws;
  u16* xb   = (u16*)(ws);              // [4096][1024] bf16
  u16* Wat  = (u16*)(ws + 8388608);    // [3072][1024] bf16 (W_attn^T, Q rows pre-scaled)
  u16* Wpt  = (u16*)(ws + 14680064);   // [1024][1024] bf16 (W_proj^T)
  u16* qkvb = (u16*)(ws + 16777216);   // [4096][3072] bf16 (V third unused)
  u16* Vt   = (u16*)(ws + 41943040);   // [32][64][2048] bf16, virtual-k permuted per 64-tile
  u16* yb   = (u16*)(ws + 50331648);   // [4096][1024] bf16

  const float CS = 0.03125f * 1.44269504088896f;  // rsqrt(1024) * log2(e)
  prep_kernel<<<5120, 256, 0, stream>>>(x, xb, Wa, Wat, Wp, Wpt, CS);
  gemm_qkv<<<768, 256, 0, stream>>>(xb, Wat, qkvb, Vt, 3072, 1024);
  attn_kernel<<<512, 512, 0, stream>>>(qkvb, Vt, yb);
  gemm_proj<<<dim3(16, 32), 256, 0, stream>>>(yb, Wpt, (float*)d_out, 1024, 1024);
}